// Round 2
// baseline (219.628 us; speedup 1.0000x reference)
//
#include <hip/hip_runtime.h>

#define NMOL 16
#define NAT  512
#define NK   27
#define NCHUNK (NMOL * NK)   // 432 chunks of 512 atoms
#define NBLK 1024            // 4 blocks/CU -- guaranteed co-resident with 2x margin

// Bit-exact float32 constants matching the numpy reference on host:
//   inv_cell diagonal = 1/20 correctly rounded = 0.05f (0x3D4CCCCD)
//   mask: dist<5.0 with correctly-rounded sqrt  <=>  ss < pred(25.0f) = 0x41C7FFFF
#define SSMAX 24.999998092651367f

__device__ __forceinline__ float wrap1(float v) {
    // proj = rn(v*0.05f); coords in [0,20) => proj<1 => woff=0, frac=proj
    // wrapped = rn(frac*20)
    return __fmul_rn(__fmul_rn(v, 0.05f), 20.0f);
}

// Candidate (unique possible) image per component + exact-mask squared distance
// test. Returns kk in 0..26 on hit, 31 on miss.
__device__ __forceinline__ int probe_code(float wx, float wy, float wz,
                                          float4 wj, bool self) {
    float dx = __fsub_rn(wx, wj.x);
    float dy = __fsub_rn(wy, wj.y);
    float dz = __fsub_rn(wz, wj.z);
    int ox = (dx > 15.0f) ? -1 : ((dx < -15.0f) ? 1 : 0);
    int oy = (dy > 15.0f) ? -1 : ((dy < -15.0f) ? 1 : 0);
    int oz = (dz > 15.0f) ? -1 : ((dz < -15.0f) ? 1 : 0);
    float ax = __fadd_rn(dx, 20.0f * (float)ox);
    float ay = __fadd_rn(dy, 20.0f * (float)oy);
    float az = __fadd_rn(dz, 20.0f * (float)oz);
    float ss = __fadd_rn(__fadd_rn(__fmul_rn(ax, ax), __fmul_rn(ay, ay)),
                         __fmul_rn(az, az));
    bool hit = (ss < SSMAX) && !self;
    int kk = (ox + 1) * 9 + (oy + 1) * 3 + (oz + 1);
    return hit ? kk : 31;
}

// Grid-wide barrier: monotonic counter, device(agent)-scope release/acquire.
// The agent-scope atomics emit the L2 writeback/invalidate required for
// cross-XCD visibility of the plain global stores made before the barrier.
// Counter is zeroed each launch by a hipMemsetAsync enqueued before the kernel.
__device__ __forceinline__ void grid_barrier(int* ctr, int target) {
    __syncthreads();   // all waves' stores drained (vmcnt) before lane-0 release
    if (threadIdx.x == 0) {
        __hip_atomic_fetch_add(ctr, 1, __ATOMIC_ACQ_REL, __HIP_MEMORY_SCOPE_AGENT);
        while (__hip_atomic_load(ctr, __ATOMIC_ACQUIRE, __HIP_MEMORY_SCOPE_AGENT) < target)
            __builtin_amdgcn_s_sleep(8);
    }
    __syncthreads();
}

// Single fused kernel, normal launch.
//   1024 blocks x 256 thr; block owns 8 atoms (2 old units) of one molecule.
//   LDS/block: 8KB raw coords + 8KB (wrapped UNION scan buf) + cur = 17.3KB
//   launch_bounds(256,4): VGPR<=128 -> 16 waves/CU -> 4 blocks/CU co-resident.
__global__ __launch_bounds__(256, 4) void fused(const float* __restrict__ coords,
                                                int* __restrict__ cnt,
                                                int* __restrict__ sums,
                                                int* __restrict__ bar,
                                                float* __restrict__ out, int P) {
    __shared__ float r4[NAT * 4];                              // raw (all phases)
    __shared__ union { float w4[NAT * 4]; int sbuf[512]; } u;  // wrapped / scan
    __shared__ int cur[2][4][NK];                              // counts / cursors

    const int blk  = blockIdx.x;
    const int m    = blk >> 6;            // 64 blocks per molecule
    const int g0   = (blk & 63) * 2;      // first of two 4-atom groups
    const int t    = threadIdx.x;
    const int w    = t >> 6;              // wave id 0..3
    const int lane = t & 63;
    const int iA   = g0 * 4 + w;          // wave's two atoms
    const int iB   = iA + 4;

    // ---------------- phase 1: stage, probe both atoms, count ----------------
    const float* cm = coords + (size_t)m * NAT * 3;
    for (int q = t; q < NAT * 3; q += 256) {
        int a = q / 3, c = q - a * 3;
        float v = cm[q];
        r4[a * 4 + c] = v;
        u.w4[a * 4 + c] = wrap1(v);
    }
    if (t < 2 * 4 * NK) ((int*)cur)[t] = 0;
    __syncthreads();

    const float wxA = u.w4[iA * 4 + 0], wyA = u.w4[iA * 4 + 1], wzA = u.w4[iA * 4 + 2];
    const float wxB = u.w4[iB * 4 + 0], wyB = u.w4[iB * 4 + 1], wzB = u.w4[iB * 4 + 2];
    const float4* w4p = reinterpret_cast<const float4*>(u.w4);

    unsigned long long codeA = 0, codeB = 0;   // byte per j-iter: kk or 31
    #pragma unroll
    for (int it = 0; it < NAT / 64; ++it) {
        const int j = it * 64 + lane;
        float4 wj = w4p[j];
        int cA = probe_code(wxA, wyA, wzA, wj, j == iA);
        int cB = probe_code(wxB, wyB, wzB, wj, j == iB);
        codeA |= (unsigned long long)cA << (8 * it);
        codeB |= (unsigned long long)cB << (8 * it);
        if (cA != 31) atomicAdd(&cur[0][w][cA], 1);
        if (cB != 31) atomicAdd(&cur[1][w][cB], 1);
    }
    __syncthreads();
    if (t < 216) {
        int uu = t / 108, rem = t % 108, ww = rem / 27, k = rem % 27;
        int i = (g0 + uu) * 4 + ww;
        cnt[(m * NK + k) * NAT + i] = cur[uu][ww][k];
    }
    grid_barrier(bar, NBLK);

    // ---------------- phase 2: per-chunk (512) exclusive scan, blocks 0..431 ----------------
    if (blk < NCHUNK) {
        int* sb = u.sbuf;                 // w4 dead: codes cached in registers
        const int i0 = blk * 512 + t;
        sb[t]       = cnt[i0];
        sb[t + 256] = cnt[i0 + 256];
        __syncthreads();
        for (int d = 1; d < 512; d <<= 1) {
            int a0 = (t >= d) ? sb[t - d] : 0;
            int a1 = sb[t + 256 - d];
            __syncthreads();
            sb[t] += a0;
            sb[t + 256] += a1;
            __syncthreads();
        }
        cnt[i0]       = (t == 0) ? 0 : sb[t - 1];   // exclusive within chunk
        cnt[i0 + 256] = sb[t + 255];
        if (t == 255) sums[blk] = sb[511];          // raw chunk total
    }
    grid_barrier(bar, 2 * NBLK);

    // ---------------- phase 3: redundant 432-total scan, then ordered emit ----------------
    {
        int v0 = sums[t];                               // t < 256 < 432
        int t2 = t + 256;
        int v1 = (t2 < NCHUNK) ? sums[t2] : 0;
        u.sbuf[t]  = v0;
        u.sbuf[t2] = v1;
    }
    __syncthreads();
    for (int d = 1; d < 512; d <<= 1) {
        int a0 = (t >= d) ? u.sbuf[t - d] : 0;
        int a1 = u.sbuf[t + 256 - d];
        __syncthreads();
        u.sbuf[t] += a0;
        u.sbuf[t + 256] += a1;
        __syncthreads();
    }
    if (t < 216) {
        int uu = t / 108, rem = t % 108, ww = rem / 27, k = rem % 27;
        int c  = m * NK + k;
        int gbase = (c == 0) ? 0 : u.sbuf[c - 1];
        int i = (g0 + uu) * 4 + ww;
        cur[uu][ww][k] = cnt[c * NAT + i] + gbase;
    }
    __syncthreads();

    const float4* r4p = reinterpret_cast<const float4*>(r4);
    const unsigned long long ltmask =
        (lane == 0) ? 0ull : (~0ull >> (64 - lane));

    #pragma unroll
    for (int uu = 0; uu < 2; ++uu) {
        const int i  = (g0 + uu) * 4 + w;
        const float rx = r4[i * 4 + 0], ry = r4[i * 4 + 1], rz = r4[i * 4 + 2];
        const int pf = m * NAT + i;
        const unsigned long long code8 = (uu == 0) ? codeA : codeB;

        #pragma unroll
        for (int it = 0; it < NAT / 64; ++it) {
            const int j = it * 64 + lane;
            int code = (int)((code8 >> (8 * it)) & 0xffull);
            bool hit = (code != 31);
            int kk = hit ? code : 0;

            // match-any over 5-bit kk among hitting lanes
            unsigned long long grp = __ballot(hit);
            #pragma unroll
            for (int b = 0; b < 5; ++b) {
                unsigned long long bm = __ballot((kk >> b) & 1);
                grp &= ((kk >> b) & 1) ? bm : ~bm;
            }
            int leader = hit ? (__ffsll((unsigned long long)grp) - 1) : 0;
            int cntg   = __popcll(grp);
            int rank   = __popcll(grp & ltmask);

            int base = 0;
            if (hit && lane == leader)
                base = atomicAdd(&cur[uu][w][kk], cntg);   // ds_add_rtn
            base = __shfl(base, leader, 64);               // broadcast from leader

            if (hit) {
                int p = base + rank;
                if (p < P) {
                    int ox = kk / 9;
                    int rem = kk - ox * 9;
                    int oy = rem / 3;
                    int oz = rem - oy * 3;
                    ox -= 1; oy -= 1; oz -= 1;
                    float cx = 20.0f * (float)ox;
                    float cy = 20.0f * (float)oy;
                    float cz = 20.0f * (float)oz;
                    float4 rj = r4p[j];
                    float px = __fadd_rn(__fsub_rn(rx, rj.x), cx);
                    float py = __fadd_rn(__fsub_rn(ry, rj.y), cy);
                    float pz = __fadd_rn(__fsub_rn(rz, rj.z), cz);
                    float ss = __fadd_rn(__fadd_rn(__fmul_rn(px, px), __fmul_rn(py, py)),
                                         __fmul_rn(pz, pz));
                    out[p]                 = __fsqrt_rn(ss);        // distflat2
                    out[P + p]             = (float)pf;             // pair_first
                    out[2 * P + p]         = (float)(m * NAT + j);  // pair_second
                    out[3 * P + 3 * p + 0] = px;                    // paircoord
                    out[3 * P + 3 * p + 1] = py;
                    out[3 * P + 3 * p + 2] = pz;
                    out[6 * P + 3 * p + 0] = (float)ox;             // offsets
                    out[6 * P + 3 * p + 1] = (float)oy;
                    out[6 * P + 3 * p + 2] = (float)oz;
                    out[9 * P + p]         = (float)kk;             // offset_index
                }
            }
        }
    }
}

extern "C" void kernel_launch(void* const* d_in, const int* in_sizes, int n_in,
                              void* d_out, int out_size, void* d_ws, size_t ws_size,
                              hipStream_t stream) {
    (void)in_sizes; (void)n_in; (void)ws_size;
    const float* coords = (const float*)d_in[0];
    int* cnt  = (int*)d_ws;               // NMOL*NK*NAT ints
    int* sums = cnt + NMOL * NK * NAT;    // NCHUNK ints (raw chunk totals)
    int* bar  = sums + 448;               // barrier counter (64B-aligned region)
    float* out = (float*)d_out;
    int P = out_size / 10;

    // zero the barrier counter each launch (capture-legal, stream-ordered)
    hipMemsetAsync(bar, 0, 64, stream);
    hipLaunchKernelGGL(fused, dim3(NBLK), dim3(256), 0, stream,
                       coords, cnt, sums, bar, out, P);
}

// Round 3
// 97.706 us; speedup vs baseline: 2.2478x; 2.2478x over previous
//
#include <hip/hip_runtime.h>

#define NMOL 16
#define NAT  512
#define NK   27
#define NCHUNK (NMOL * NK)   // 432 chunks of 512 atoms

// Bit-exact float32 constants matching the numpy reference on host:
//   inv_cell diagonal = 1/20 correctly rounded = 0.05f (0x3D4CCCCD)
//   mask: dist<5.0 with correctly-rounded sqrt  <=>  ss < pred(25.0f) = 0x41C7FFFF
#define SSMAX 24.999998092651367f

__device__ __forceinline__ float wrap1(float v) {
    // proj = rn(v*0.05f); coords in [0,20) => proj<1 => woff=0, frac=proj
    // wrapped = rn(frac*20)
    return __fmul_rn(__fmul_rn(v, 0.05f), 20.0f);
}

// Candidate (unique possible) image per component + exact-mask squared distance
// test. Returns kk in 0..26 on hit, 31 on miss.
__device__ __forceinline__ int probe_code(float wx, float wy, float wz,
                                          float wjx, float wjy, float wjz,
                                          bool self) {
    float dx = __fsub_rn(wx, wjx);
    float dy = __fsub_rn(wy, wjy);
    float dz = __fsub_rn(wz, wjz);
    int ox = (dx > 15.0f) ? -1 : ((dx < -15.0f) ? 1 : 0);
    int oy = (dy > 15.0f) ? -1 : ((dy < -15.0f) ? 1 : 0);
    int oz = (dz > 15.0f) ? -1 : ((dz < -15.0f) ? 1 : 0);
    float ax = __fadd_rn(dx, 20.0f * (float)ox);
    float ay = __fadd_rn(dy, 20.0f * (float)oy);
    float az = __fadd_rn(dz, 20.0f * (float)oz);
    float ss = __fadd_rn(__fadd_rn(__fmul_rn(ax, ax), __fmul_rn(ay, ay)),
                         __fmul_rn(az, az));
    bool hit = (ss < SSMAX) && !self;
    return hit ? ((ox + 1) * 9 + (oy + 1) * 3 + (oz + 1)) : 31;
}

// ---------------- Pass A: count hits per (m, k, i) ----------------
// 1024 blocks x 256 thr; block owns 8 atoms (2 per wave) of one molecule.
// Raw coords staged PACKED (float[1536]) via pure float4 copy; wrapped coords
// computed on the fly (2 VALU/component), shared between the wave's 2 atoms.
__global__ __launch_bounds__(256, 8) void pass_count(const float* __restrict__ coords,
                                                     int* __restrict__ cnt) {
    __shared__ float rr[NAT * 3];
    __shared__ int cur[2][4][NK];
    const int blk  = blockIdx.x;
    const int m    = blk >> 6;            // 64 blocks per molecule
    const int g0   = (blk & 63) * 2;
    const int t    = threadIdx.x;
    const int w    = t >> 6;
    const int lane = t & 63;
    const int iA   = g0 * 4 + w;
    const int iB   = iA + 4;

    const float4* cm4 = reinterpret_cast<const float4*>(coords + (size_t)m * NAT * 3);
    float4* rr4 = reinterpret_cast<float4*>(rr);
    rr4[t] = cm4[t];                       // 384 float4 total
    if (t < 128) rr4[t + 256] = cm4[t + 256];
    if (t < 2 * 4 * NK) ((int*)cur)[t] = 0;
    __syncthreads();

    const float wAx = wrap1(rr[iA * 3 + 0]), wAy = wrap1(rr[iA * 3 + 1]), wAz = wrap1(rr[iA * 3 + 2]);
    const float wBx = wrap1(rr[iB * 3 + 0]), wBy = wrap1(rr[iB * 3 + 1]), wBz = wrap1(rr[iB * 3 + 2]);

    #pragma unroll
    for (int it = 0; it < NAT / 64; ++it) {
        const int j = it * 64 + lane;
        float wjx = wrap1(rr[j * 3 + 0]);
        float wjy = wrap1(rr[j * 3 + 1]);
        float wjz = wrap1(rr[j * 3 + 2]);
        int cA = probe_code(wAx, wAy, wAz, wjx, wjy, wjz, j == iA);
        int cB = probe_code(wBx, wBy, wBz, wjx, wjy, wjz, j == iB);
        if (cA != 31) atomicAdd(&cur[0][w][cA], 1);
        if (cB != 31) atomicAdd(&cur[1][w][cB], 1);
    }
    __syncthreads();
    if (t < 216) {
        int uu = t / 108, rem = t % 108, ww = rem / 27, k = rem % 27;
        int i = (g0 + uu) * 4 + ww;
        cnt[(m * NK + k) * NAT + i] = cur[uu][ww][k];
    }
}

// ---------------- Pass B: per-chunk (512) exclusive scan, shuffle-based ----------------
// 2 barriers instead of 36. Integer math identical to the Hillis-Steele version.
__global__ __launch_bounds__(512) void scan_chunk(int* __restrict__ cnt,
                                                  int* __restrict__ sums) {
    __shared__ int wsum[8], wexc[9];
    const int c = blockIdx.x;
    const int t = threadIdx.x;
    const int w = t >> 6;
    const int lane = t & 63;
    const int idx = c * 512 + t;
    const int orig = cnt[idx];
    int v = orig;
    #pragma unroll
    for (int d = 1; d < 64; d <<= 1) {       // inclusive wave scan
        int u = __shfl_up(v, d, 64);
        if (lane >= d) v += u;
    }
    if (lane == 63) wsum[w] = v;
    __syncthreads();
    if (t < 8) {
        int s = 0;
        for (int q = 0; q < t; ++q) s += wsum[q];
        wexc[t] = s;
        if (t == 7) wexc[8] = s + wsum[7];   // chunk total
    }
    __syncthreads();
    cnt[idx] = wexc[w] + (v - orig);         // exclusive within chunk
    if (t == 0) sums[c] = wexc[8];           // raw total, NOT scanned
}

// ---------------- Pass C: recompute selection, emit outputs in exact order ----------------
// Block self-scans the 432 chunk totals (shuffle-based, 3 barriers) for the
// global (m,k) base; ordered ranks within (i,k) via ballot match-any + leader
// LDS fetch-and-add + shfl broadcast (verified logic from prior rounds).
__global__ __launch_bounds__(256, 8) void pass_emit(const float* __restrict__ coords,
                                                    const int* __restrict__ cnt,
                                                    const int* __restrict__ sums,
                                                    float* __restrict__ out, int P) {
    __shared__ float rr[NAT * 3];
    __shared__ int sbuf[NCHUNK];             // exclusive scan of 432 chunk totals
    __shared__ int wsum4[4], wexc4[4];
    __shared__ int cur[2][4][NK];
    const int blk  = blockIdx.x;
    const int m    = blk >> 6;
    const int g0   = (blk & 63) * 2;
    const int t    = threadIdx.x;
    const int w    = t >> 6;
    const int lane = t & 63;

    // stage raw packed + load chunk totals (pairs 2t,2t+1) in flight together
    const float4* cm4 = reinterpret_cast<const float4*>(coords + (size_t)m * NAT * 3);
    float4* rr4 = reinterpret_cast<float4*>(rr);
    rr4[t] = cm4[t];
    if (t < 128) rr4[t + 256] = cm4[t + 256];

    const int e0 = 2 * t;
    int v0 = (e0 < NCHUNK) ? sums[e0] : 0;
    int v1 = (e0 + 1 < NCHUNK) ? sums[e0 + 1] : 0;
    const int ps = v0 + v1;
    int incl = ps;
    #pragma unroll
    for (int d = 1; d < 64; d <<= 1) {       // inclusive wave scan over pair sums
        int u = __shfl_up(incl, d, 64);
        if (lane >= d) incl += u;
    }
    if (lane == 63) wsum4[w] = incl;
    __syncthreads();
    if (t < 4) {
        int s = 0;
        for (int q = 0; q < t; ++q) s += wsum4[q];
        wexc4[t] = s;
    }
    __syncthreads();
    const int pe = wexc4[w] + (incl - ps);   // exclusive over elements < e0
    if (e0 < NCHUNK)     sbuf[e0]     = pe;
    if (e0 + 1 < NCHUNK) sbuf[e0 + 1] = pe + v0;
    __syncthreads();
    if (t < 216) {
        int uu = t / 108, rem = t % 108, ww = rem / 27, k = rem % 27;
        int c  = m * NK + k;
        int i  = (g0 + uu) * 4 + ww;
        cur[uu][ww][k] = cnt[c * NAT + i] + sbuf[c];   // global cursor base
    }
    __syncthreads();

    // own-atom raw + wrapped
    const int iA = g0 * 4 + w, iB = iA + 4;
    const float rAx = rr[iA * 3 + 0], rAy = rr[iA * 3 + 1], rAz = rr[iA * 3 + 2];
    const float rBx = rr[iB * 3 + 0], rBy = rr[iB * 3 + 1], rBz = rr[iB * 3 + 2];
    const float wAx = wrap1(rAx), wAy = wrap1(rAy), wAz = wrap1(rAz);
    const float wBx = wrap1(rBx), wBy = wrap1(rBy), wBz = wrap1(rBz);
    const unsigned long long ltmask =
        (lane == 0) ? 0ull : (~0ull >> (64 - lane));

    #pragma unroll
    for (int it = 0; it < NAT / 64; ++it) {
        const int j = it * 64 + lane;
        const float rjx = rr[j * 3 + 0], rjy = rr[j * 3 + 1], rjz = rr[j * 3 + 2];
        const float wjx = wrap1(rjx), wjy = wrap1(rjy), wjz = wrap1(rjz);

        #pragma unroll
        for (int uu = 0; uu < 2; ++uu) {
            const int i  = (uu == 0) ? iA : iB;
            const float rx = (uu == 0) ? rAx : rBx;
            const float ry = (uu == 0) ? rAy : rBy;
            const float rz = (uu == 0) ? rAz : rBz;
            int code = (uu == 0)
                ? probe_code(wAx, wAy, wAz, wjx, wjy, wjz, j == iA)
                : probe_code(wBx, wBy, wBz, wjx, wjy, wjz, j == iB);
            bool hit = (code != 31);
            int kk = hit ? code : 0;

            // match-any over 5-bit kk among hitting lanes
            unsigned long long grp = __ballot(hit);
            #pragma unroll
            for (int b = 0; b < 5; ++b) {
                unsigned long long bm = __ballot((kk >> b) & 1);
                grp &= ((kk >> b) & 1) ? bm : ~bm;
            }
            int leader = hit ? (__ffsll((unsigned long long)grp) - 1) : 0;
            int cntg   = __popcll(grp);
            int rank   = __popcll(grp & ltmask);

            int base = 0;
            if (hit && lane == leader)
                base = atomicAdd(&cur[uu][w][kk], cntg);   // ds_add_rtn
            base = __shfl(base, leader, 64);               // broadcast from leader

            if (hit) {
                int p = base + rank;
                if (p < P) {
                    int ox = kk / 9;
                    int rem = kk - ox * 9;
                    int oy = rem / 3;
                    int oz = rem - oy * 3;
                    ox -= 1; oy -= 1; oz -= 1;
                    float cx = 20.0f * (float)ox;
                    float cy = 20.0f * (float)oy;
                    float cz = 20.0f * (float)oz;
                    float px = __fadd_rn(__fsub_rn(rx, rjx), cx);
                    float py = __fadd_rn(__fsub_rn(ry, rjy), cy);
                    float pz = __fadd_rn(__fsub_rn(rz, rjz), cz);
                    float ss = __fadd_rn(__fadd_rn(__fmul_rn(px, px), __fmul_rn(py, py)),
                                         __fmul_rn(pz, pz));
                    out[p]                 = __fsqrt_rn(ss);        // distflat2
                    out[P + p]             = (float)(m * NAT + i);  // pair_first
                    out[2 * P + p]         = (float)(m * NAT + j);  // pair_second
                    out[3 * P + 3 * p + 0] = px;                    // paircoord
                    out[3 * P + 3 * p + 1] = py;
                    out[3 * P + 3 * p + 2] = pz;
                    out[6 * P + 3 * p + 0] = (float)ox;             // offsets
                    out[6 * P + 3 * p + 1] = (float)oy;
                    out[6 * P + 3 * p + 2] = (float)oz;
                    out[9 * P + p]         = (float)kk;             // offset_index
                }
            }
        }
    }
}

extern "C" void kernel_launch(void* const* d_in, const int* in_sizes, int n_in,
                              void* d_out, int out_size, void* d_ws, size_t ws_size,
                              hipStream_t stream) {
    (void)in_sizes; (void)n_in; (void)ws_size;
    const float* coords = (const float*)d_in[0];
    int* cnt  = (int*)d_ws;               // NMOL*NK*NAT ints
    int* sums = cnt + NMOL * NK * NAT;    // NCHUNK ints (raw chunk totals)
    float* out = (float*)d_out;
    const int P = out_size / 10;

    hipLaunchKernelGGL(pass_count, dim3(NMOL * NAT / 8), dim3(256), 0, stream, coords, cnt);
    hipLaunchKernelGGL(scan_chunk, dim3(NCHUNK), dim3(512), 0, stream, cnt, sums);
    hipLaunchKernelGGL(pass_emit, dim3(NMOL * NAT / 8), dim3(256), 0, stream,
                       coords, cnt, sums, out, P);
}